// Round 1
// baseline (1441.992 us; speedup 1.0000x reference)
//
#include <hip/hip_runtime.h>

#define TT 100
#define BB 2048
#define NI 3
#define NU 128
#define NB 256
#define NPC 256
#define NHD 12

__device__ __forceinline__ float fast_sigmoid(float x) {
  return 1.0f / (1.0f + __expf(-x));
}
__device__ __forceinline__ float fast_tanh(float x) {
  // 1 - 2/(e^{2x}+1); saturates correctly for large |x|
  return 1.0f - 2.0f / (__expf(2.0f * x) + 1.0f);
}
__device__ __forceinline__ float dot4(float4 h, float u0, float u1, float u2,
                                      float u3, float acc) {
  acc = fmaf(h.x, u0, acc);
  acc = fmaf(h.y, u1, acc);
  acc = fmaf(h.z, u2, acc);
  acc = fmaf(h.w, u3, acc);
  return acc;
}

// ---------------------------------------------------------------------------
// h0 = concat(init_pc, init_hd) @ W_embed + b_embed     [B, NU]
// block = 256 threads = 2 rows x 128 cols
// ---------------------------------------------------------------------------
__global__ __launch_bounds__(256) void embed_kernel(
    const float* __restrict__ init_pc, const float* __restrict__ init_hd,
    const float* __restrict__ W_embed, const float* __restrict__ b_embed,
    float* __restrict__ h0) {
  __shared__ float pcs[2][NPC];
  __shared__ float hds[2][NHD];
  const int tid = threadIdx.x;
  const int b0 = blockIdx.x * 2;

  for (int idx = tid; idx < 2 * NPC; idx += 256)
    pcs[idx >> 8][idx & 255] =
        init_pc[(size_t)(b0 + (idx >> 8)) * NPC + (idx & 255)];
  if (tid < 2 * NHD) {
    int rr = tid / NHD, cc = tid - rr * NHD;
    hds[rr][cc] = init_hd[(size_t)(b0 + rr) * NHD + cc];
  }
  __syncthreads();

  const int half = tid >> 7;
  const int j = tid & 127;
  const float* Wp = W_embed + j;
  float a0 = 0.f, a1 = 0.f, a2 = 0.f, a3 = 0.f;
#pragma unroll 4
  for (int k = 0; k < NPC; k += 4) {
    a0 = fmaf(pcs[half][k + 0], Wp[(k + 0) * NU], a0);
    a1 = fmaf(pcs[half][k + 1], Wp[(k + 1) * NU], a1);
    a2 = fmaf(pcs[half][k + 2], Wp[(k + 2) * NU], a2);
    a3 = fmaf(pcs[half][k + 3], Wp[(k + 3) * NU], a3);
  }
#pragma unroll
  for (int k = 0; k < NHD; ++k)
    a0 = fmaf(hds[half][k], Wp[(NPC + k) * NU], a0);
  float acc = b_embed[j] + ((a0 + a1) + (a2 + a3));
  h0[(size_t)(b0 + half) * NU + j] = acc;
}

// ---------------------------------------------------------------------------
// GRU scan. Each block owns 8 batch rows for all T steps; h lives in LDS.
// 512 threads. Phase1: z & r gates (g = tid>>8), 4 rows x 1 col per thread.
// Phase3: h-tilde + update, 2 rows x 1 col per thread.
// U matrices streamed from L2 each step (coalesced over j).
// ---------------------------------------------------------------------------
__global__ __launch_bounds__(512, 2) void gru_kernel(
    const float* __restrict__ x, const float* __restrict__ h0,
    const float* __restrict__ Wz, const float* __restrict__ Wr,
    const float* __restrict__ Wh, const float* __restrict__ Uz,
    const float* __restrict__ Ur, const float* __restrict__ Uh,
    const float* __restrict__ bz, const float* __restrict__ br,
    const float* __restrict__ bh, float* __restrict__ states,
    float* __restrict__ final_state) {
  __shared__ float h_lds[8][NU];
  __shared__ float z_lds[8][NU];
  __shared__ float rh_lds[8][NU];
  __shared__ float wx_lds[3][NI][NU];
  __shared__ float bias_lds[3][NU];
  __shared__ float xt_lds[2][8][4];

  const int tid = threadIdx.x;
  const int row0 = blockIdx.x * 8;

  for (int idx = tid; idx < 3 * NI * NU; idx += 512) {
    int g = idx / (NI * NU), rem = idx - g * (NI * NU);
    const float* W = (g == 0) ? Wz : (g == 1) ? Wr : Wh;
    wx_lds[g][rem >> 7][rem & 127] = W[rem];
  }
  if (tid < NU) {
    bias_lds[0][tid] = bz[tid];
    bias_lds[1][tid] = br[tid];
    bias_lds[2][tid] = bh[tid];
  }
  for (int idx = tid; idx < 8 * NU; idx += 512)
    h_lds[idx >> 7][idx & 127] = h0[(size_t)row0 * NU + idx];

  const int g = tid >> 8;                 // phase1 gate: 0=z, 1=r
  const int sub = tid & 255;
  const int j = tid & 127;
  const int r0p1 = (sub >> 7) * 4;        // phase1 row base (4 rows)
  const int r0p3 = ((tid >> 7) & 3) * 2;  // phase3 row base (2 rows)
  const float* Up1 = (g ? Ur : Uz) + j;
  const float* Up3 = Uh + j;

  for (int t = 0; t < TT; ++t) {
    const int pb = t & 1;
    if (tid < 24) {
      int r = tid / 3, i = tid - r * 3;
      xt_lds[pb][r][i] = x[(size_t)(t * BB + row0 + r) * NI + i];
    }
    __syncthreads();  // h (prev step) + xt visible

    // ---- phase 1: z (g==0) and r (g==1) for 4 rows ----
    {
      float b = bias_lds[g][j];
      float a0 = b, a1 = b, a2 = b, a3 = b;
#pragma unroll
      for (int i = 0; i < NI; ++i) {
        float w = wx_lds[g][i][j];
        a0 = fmaf(xt_lds[pb][r0p1 + 0][i], w, a0);
        a1 = fmaf(xt_lds[pb][r0p1 + 1][i], w, a1);
        a2 = fmaf(xt_lds[pb][r0p1 + 2][i], w, a2);
        a3 = fmaf(xt_lds[pb][r0p1 + 3][i], w, a3);
      }
#pragma unroll 4
      for (int k = 0; k < NU; k += 4) {
        const float4 h0v = *(const float4*)&h_lds[r0p1 + 0][k];
        const float4 h1v = *(const float4*)&h_lds[r0p1 + 1][k];
        const float4 h2v = *(const float4*)&h_lds[r0p1 + 2][k];
        const float4 h3v = *(const float4*)&h_lds[r0p1 + 3][k];
        const float u0 = Up1[(k + 0) * NU];
        const float u1 = Up1[(k + 1) * NU];
        const float u2 = Up1[(k + 2) * NU];
        const float u3 = Up1[(k + 3) * NU];
        a0 = dot4(h0v, u0, u1, u2, u3, a0);
        a1 = dot4(h1v, u0, u1, u2, u3, a1);
        a2 = dot4(h2v, u0, u1, u2, u3, a2);
        a3 = dot4(h3v, u0, u1, u2, u3, a3);
      }
      if (g == 0) {
        z_lds[r0p1 + 0][j] = fast_sigmoid(a0);
        z_lds[r0p1 + 1][j] = fast_sigmoid(a1);
        z_lds[r0p1 + 2][j] = fast_sigmoid(a2);
        z_lds[r0p1 + 3][j] = fast_sigmoid(a3);
      } else {
        rh_lds[r0p1 + 0][j] = fast_sigmoid(a0) * h_lds[r0p1 + 0][j];
        rh_lds[r0p1 + 1][j] = fast_sigmoid(a1) * h_lds[r0p1 + 1][j];
        rh_lds[r0p1 + 2][j] = fast_sigmoid(a2) * h_lds[r0p1 + 2][j];
        rh_lds[r0p1 + 3][j] = fast_sigmoid(a3) * h_lds[r0p1 + 3][j];
      }
    }
    __syncthreads();  // z, rh visible

    // ---- phase 3: h-tilde + state update for 2 rows ----
    {
      float b = bias_lds[2][j];
      float a0 = b, a1 = b;
#pragma unroll
      for (int i = 0; i < NI; ++i) {
        float w = wx_lds[2][i][j];
        a0 = fmaf(xt_lds[pb][r0p3 + 0][i], w, a0);
        a1 = fmaf(xt_lds[pb][r0p3 + 1][i], w, a1);
      }
#pragma unroll 4
      for (int k = 0; k < NU; k += 4) {
        const float4 p0 = *(const float4*)&rh_lds[r0p3 + 0][k];
        const float4 p1 = *(const float4*)&rh_lds[r0p3 + 1][k];
        const float u0 = Up3[(k + 0) * NU];
        const float u1 = Up3[(k + 1) * NU];
        const float u2 = Up3[(k + 2) * NU];
        const float u3 = Up3[(k + 3) * NU];
        a0 = dot4(p0, u0, u1, u2, u3, a0);
        a1 = dot4(p1, u0, u1, u2, u3, a1);
      }
#pragma unroll
      for (int rr = 0; rr < 2; ++rr) {
        float pre = rr ? a1 : a0;
        float htw = fast_tanh(pre);
        int r = r0p3 + rr;
        float hold = h_lds[r][j];
        float zz = z_lds[r][j];
        float hnew = fmaf(zz, htw - hold, hold);  // (1-z)h + z*htw
        h_lds[r][j] = hnew;
        states[(size_t)(t * BB + row0 + r) * NU + j] = hnew;
      }
    }
    // no barrier here: next iter's top barrier orders h writes vs reads;
    // xt is double-buffered.
  }
  __syncthreads();
  for (int idx = tid; idx < 8 * NU; idx += 512)
    final_state[(size_t)row0 * NU + idx] = h_lds[idx >> 7][idx & 127];
}

// ---------------------------------------------------------------------------
// Fused heads: per 16 rows of states -> bneck (LDS + out), logits_pc, logits_hd
// 256 threads: 4 rows x 4 cols per thread for the 256-wide GEMMs.
// ---------------------------------------------------------------------------
__global__ __launch_bounds__(256, 2) void heads_kernel(
    const float* __restrict__ states, const float* __restrict__ W_bneck,
    const float* __restrict__ W_pc, const float* __restrict__ b_pc,
    const float* __restrict__ W_hd, const float* __restrict__ b_hd,
    float* __restrict__ out_hd, float* __restrict__ out_pc,
    float* __restrict__ out_bn) {
  __shared__ float s_lds[16][NU];
  __shared__ float bn_lds[16][NB];
  const int tid = threadIdx.x;
  const size_t r0 = (size_t)blockIdx.x * 16;

  {
    const float4* src = (const float4*)(states + r0 * NU);
    float4* dst = (float4*)s_lds;
    for (int idx = tid; idx < 16 * NU / 4; idx += 256) dst[idx] = src[idx];
  }
  __syncthreads();

  const int jc = (tid & 63) * 4;
  const int rg = (tid >> 6) * 4;

  // ---- bottleneck: states[16,128] @ W_bneck[128,256] (no bias) ----
  {
    float acc[4][4];
#pragma unroll
    for (int a = 0; a < 4; ++a)
#pragma unroll
      for (int c = 0; c < 4; ++c) acc[a][c] = 0.0f;
    const float* Wp = W_bneck + jc;
#pragma unroll 4
    for (int k = 0; k < NU; k += 4) {
      const float4 w0 = *(const float4*)&Wp[(k + 0) * NB];
      const float4 w1 = *(const float4*)&Wp[(k + 1) * NB];
      const float4 w2 = *(const float4*)&Wp[(k + 2) * NB];
      const float4 w3 = *(const float4*)&Wp[(k + 3) * NB];
#pragma unroll
      for (int a = 0; a < 4; ++a) {
        const float4 s = *(const float4*)&s_lds[rg + a][k];
        acc[a][0] = dot4(s, w0.x, w1.x, w2.x, w3.x, acc[a][0]);
        acc[a][1] = dot4(s, w0.y, w1.y, w2.y, w3.y, acc[a][1]);
        acc[a][2] = dot4(s, w0.z, w1.z, w2.z, w3.z, acc[a][2]);
        acc[a][3] = dot4(s, w0.w, w1.w, w2.w, w3.w, acc[a][3]);
      }
    }
#pragma unroll
    for (int a = 0; a < 4; ++a) {
      float4 v = make_float4(acc[a][0], acc[a][1], acc[a][2], acc[a][3]);
      *(float4*)&bn_lds[rg + a][jc] = v;
      *(float4*)&out_bn[(r0 + rg + a) * NB + jc] = v;
    }
  }
  __syncthreads();

  // ---- logits_pc: bneck[16,256] @ W_pc[256,256] + b_pc ----
  {
    const float4 bp = *(const float4*)&b_pc[jc];
    float acc[4][4];
#pragma unroll
    for (int a = 0; a < 4; ++a) {
      acc[a][0] = bp.x;
      acc[a][1] = bp.y;
      acc[a][2] = bp.z;
      acc[a][3] = bp.w;
    }
    const float* Wp = W_pc + jc;
#pragma unroll 4
    for (int k = 0; k < NB; k += 4) {
      const float4 w0 = *(const float4*)&Wp[(k + 0) * NPC];
      const float4 w1 = *(const float4*)&Wp[(k + 1) * NPC];
      const float4 w2 = *(const float4*)&Wp[(k + 2) * NPC];
      const float4 w3 = *(const float4*)&Wp[(k + 3) * NPC];
#pragma unroll
      for (int a = 0; a < 4; ++a) {
        const float4 s = *(const float4*)&bn_lds[rg + a][k];
        acc[a][0] = dot4(s, w0.x, w1.x, w2.x, w3.x, acc[a][0]);
        acc[a][1] = dot4(s, w0.y, w1.y, w2.y, w3.y, acc[a][1]);
        acc[a][2] = dot4(s, w0.z, w1.z, w2.z, w3.z, acc[a][2]);
        acc[a][3] = dot4(s, w0.w, w1.w, w2.w, w3.w, acc[a][3]);
      }
    }
#pragma unroll
    for (int a = 0; a < 4; ++a) {
      float4 v = make_float4(acc[a][0], acc[a][1], acc[a][2], acc[a][3]);
      *(float4*)&out_pc[(r0 + rg + a) * NPC + jc] = v;
    }
  }

  // ---- logits_hd: bneck[16,256] @ W_hd[256,12] + b_hd ----
  if (tid < 16 * NHD) {
    const int r = tid / NHD;
    const int c = tid - r * NHD;
    float acc = b_hd[c];
#pragma unroll 4
    for (int k = 0; k < NB; ++k)
      acc = fmaf(bn_lds[r][k], W_hd[k * NHD + c], acc);
    out_hd[(r0 + r) * NHD + c] = acc;
  }
}

// ---------------------------------------------------------------------------
extern "C" void kernel_launch(void* const* d_in, const int* in_sizes, int n_in,
                              void* d_out, int out_size, void* d_ws,
                              size_t ws_size, hipStream_t stream) {
  (void)in_sizes;
  (void)n_in;
  (void)out_size;
  (void)ws_size;
  const float* x = (const float*)d_in[0];
  const float* init_pc = (const float*)d_in[1];
  const float* init_hd = (const float*)d_in[2];
  const float* Wz = (const float*)d_in[3];
  const float* Wr = (const float*)d_in[4];
  const float* Wh = (const float*)d_in[5];
  const float* Uz = (const float*)d_in[6];
  const float* Ur = (const float*)d_in[7];
  const float* Uh = (const float*)d_in[8];
  const float* bz = (const float*)d_in[9];
  const float* br = (const float*)d_in[10];
  const float* bh = (const float*)d_in[11];
  const float* W_embed = (const float*)d_in[12];
  const float* b_embed = (const float*)d_in[13];
  const float* W_bneck = (const float*)d_in[14];
  const float* W_pc = (const float*)d_in[15];
  const float* b_pc = (const float*)d_in[16];
  const float* W_hd = (const float*)d_in[17];
  const float* b_hd = (const float*)d_in[18];

  float* out = (float*)d_out;
  float* out_hd = out;
  float* out_pc = out_hd + (size_t)TT * BB * NHD;
  float* out_bn = out_pc + (size_t)TT * BB * NPC;
  float* out_st = out_bn + (size_t)TT * BB * NB;
  float* out_fs = out_st + (size_t)TT * BB * NU;

  float* h0 = (float*)d_ws;  // B*NU floats = 1 MB scratch

  embed_kernel<<<BB / 2, 256, 0, stream>>>(init_pc, init_hd, W_embed, b_embed,
                                           h0);
  gru_kernel<<<BB / 8, 512, 0, stream>>>(x, h0, Wz, Wr, Wh, Uz, Ur, Uh, bz, br,
                                         bh, out_st, out_fs);
  heads_kernel<<<(TT * BB) / 16, 256, 0, stream>>>(
      out_st, W_bneck, W_pc, b_pc, W_hd, b_hd, out_hd, out_pc, out_bn);
}

// Round 2
// 861.691 us; speedup vs baseline: 1.6734x; 1.6734x over previous
//
#include <hip/hip_runtime.h>

#define TT 100
#define BB 2048
#define NI 3
#define NU 128
#define NB 256
#define NPC 256
#define NHD 12

typedef __attribute__((ext_vector_type(8))) short short8;
typedef __attribute__((ext_vector_type(4))) float f32x4;

__device__ __forceinline__ float fast_sigmoid(float x) {
  return 1.0f / (1.0f + __expf(-x));
}
__device__ __forceinline__ float fast_tanh(float x) {
  return 1.0f - 2.0f / (__expf(2.0f * x) + 1.0f);
}
__device__ __forceinline__ float dot4(float4 h, float u0, float u1, float u2,
                                      float u3, float acc) {
  acc = fmaf(h.x, u0, acc);
  acc = fmaf(h.y, u1, acc);
  acc = fmaf(h.z, u2, acc);
  acc = fmaf(h.w, u3, acc);
  return acc;
}
__device__ __forceinline__ short f2bf(float f) {
  uint32_t u = __float_as_uint(f);
  u += 0x7FFF + ((u >> 16) & 1);  // RNE
  return (short)(u >> 16);
}

// ---------------------------------------------------------------------------
// h0 = concat(init_pc, init_hd) @ W_embed + b_embed     [B, NU]
// ---------------------------------------------------------------------------
__global__ __launch_bounds__(256) void embed_kernel(
    const float* __restrict__ init_pc, const float* __restrict__ init_hd,
    const float* __restrict__ W_embed, const float* __restrict__ b_embed,
    float* __restrict__ h0) {
  __shared__ float pcs[2][NPC];
  __shared__ float hds[2][NHD];
  const int tid = threadIdx.x;
  const int b0 = blockIdx.x * 2;

  for (int idx = tid; idx < 2 * NPC; idx += 256)
    pcs[idx >> 8][idx & 255] =
        init_pc[(size_t)(b0 + (idx >> 8)) * NPC + (idx & 255)];
  if (tid < 2 * NHD) {
    int rr = tid / NHD, cc = tid - rr * NHD;
    hds[rr][cc] = init_hd[(size_t)(b0 + rr) * NHD + cc];
  }
  __syncthreads();

  const int half = tid >> 7;
  const int j = tid & 127;
  const float* Wp = W_embed + j;
  float a0 = 0.f, a1 = 0.f, a2 = 0.f, a3 = 0.f;
#pragma unroll 4
  for (int k = 0; k < NPC; k += 4) {
    a0 = fmaf(pcs[half][k + 0], Wp[(k + 0) * NU], a0);
    a1 = fmaf(pcs[half][k + 1], Wp[(k + 1) * NU], a1);
    a2 = fmaf(pcs[half][k + 2], Wp[(k + 2) * NU], a2);
    a3 = fmaf(pcs[half][k + 3], Wp[(k + 3) * NU], a3);
  }
#pragma unroll
  for (int k = 0; k < NHD; ++k)
    a0 = fmaf(hds[half][k], Wp[(NPC + k) * NU], a0);
  float acc = b_embed[j] + ((a0 + a1) + (a2 + a3));
  h0[(size_t)(b0 + half) * NU + j] = acc;
}

// ---------------------------------------------------------------------------
// GRU scan (unchanged from round 1): 8 rows/block resident for all T steps.
// ---------------------------------------------------------------------------
__global__ __launch_bounds__(512, 2) void gru_kernel(
    const float* __restrict__ x, const float* __restrict__ h0,
    const float* __restrict__ Wz, const float* __restrict__ Wr,
    const float* __restrict__ Wh, const float* __restrict__ Uz,
    const float* __restrict__ Ur, const float* __restrict__ Uh,
    const float* __restrict__ bz, const float* __restrict__ br,
    const float* __restrict__ bh, float* __restrict__ states,
    float* __restrict__ final_state) {
  __shared__ float h_lds[8][NU];
  __shared__ float z_lds[8][NU];
  __shared__ float rh_lds[8][NU];
  __shared__ float wx_lds[3][NI][NU];
  __shared__ float bias_lds[3][NU];
  __shared__ float xt_lds[2][8][4];

  const int tid = threadIdx.x;
  const int row0 = blockIdx.x * 8;

  for (int idx = tid; idx < 3 * NI * NU; idx += 512) {
    int g = idx / (NI * NU), rem = idx - g * (NI * NU);
    const float* W = (g == 0) ? Wz : (g == 1) ? Wr : Wh;
    wx_lds[g][rem >> 7][rem & 127] = W[rem];
  }
  if (tid < NU) {
    bias_lds[0][tid] = bz[tid];
    bias_lds[1][tid] = br[tid];
    bias_lds[2][tid] = bh[tid];
  }
  for (int idx = tid; idx < 8 * NU; idx += 512)
    h_lds[idx >> 7][idx & 127] = h0[(size_t)row0 * NU + idx];

  const int g = tid >> 8;
  const int sub = tid & 255;
  const int j = tid & 127;
  const int r0p1 = (sub >> 7) * 4;
  const int r0p3 = ((tid >> 7) & 3) * 2;
  const float* Up1 = (g ? Ur : Uz) + j;
  const float* Up3 = Uh + j;

  for (int t = 0; t < TT; ++t) {
    const int pb = t & 1;
    if (tid < 24) {
      int r = tid / 3, i = tid - r * 3;
      xt_lds[pb][r][i] = x[(size_t)(t * BB + row0 + r) * NI + i];
    }
    __syncthreads();

    {
      float b = bias_lds[g][j];
      float a0 = b, a1 = b, a2 = b, a3 = b;
#pragma unroll
      for (int i = 0; i < NI; ++i) {
        float w = wx_lds[g][i][j];
        a0 = fmaf(xt_lds[pb][r0p1 + 0][i], w, a0);
        a1 = fmaf(xt_lds[pb][r0p1 + 1][i], w, a1);
        a2 = fmaf(xt_lds[pb][r0p1 + 2][i], w, a2);
        a3 = fmaf(xt_lds[pb][r0p1 + 3][i], w, a3);
      }
#pragma unroll 4
      for (int k = 0; k < NU; k += 4) {
        const float4 h0v = *(const float4*)&h_lds[r0p1 + 0][k];
        const float4 h1v = *(const float4*)&h_lds[r0p1 + 1][k];
        const float4 h2v = *(const float4*)&h_lds[r0p1 + 2][k];
        const float4 h3v = *(const float4*)&h_lds[r0p1 + 3][k];
        const float u0 = Up1[(k + 0) * NU];
        const float u1 = Up1[(k + 1) * NU];
        const float u2 = Up1[(k + 2) * NU];
        const float u3 = Up1[(k + 3) * NU];
        a0 = dot4(h0v, u0, u1, u2, u3, a0);
        a1 = dot4(h1v, u0, u1, u2, u3, a1);
        a2 = dot4(h2v, u0, u1, u2, u3, a2);
        a3 = dot4(h3v, u0, u1, u2, u3, a3);
      }
      if (g == 0) {
        z_lds[r0p1 + 0][j] = fast_sigmoid(a0);
        z_lds[r0p1 + 1][j] = fast_sigmoid(a1);
        z_lds[r0p1 + 2][j] = fast_sigmoid(a2);
        z_lds[r0p1 + 3][j] = fast_sigmoid(a3);
      } else {
        rh_lds[r0p1 + 0][j] = fast_sigmoid(a0) * h_lds[r0p1 + 0][j];
        rh_lds[r0p1 + 1][j] = fast_sigmoid(a1) * h_lds[r0p1 + 1][j];
        rh_lds[r0p1 + 2][j] = fast_sigmoid(a2) * h_lds[r0p1 + 2][j];
        rh_lds[r0p1 + 3][j] = fast_sigmoid(a3) * h_lds[r0p1 + 3][j];
      }
    }
    __syncthreads();

    {
      float b = bias_lds[2][j];
      float a0 = b, a1 = b;
#pragma unroll
      for (int i = 0; i < NI; ++i) {
        float w = wx_lds[2][i][j];
        a0 = fmaf(xt_lds[pb][r0p3 + 0][i], w, a0);
        a1 = fmaf(xt_lds[pb][r0p3 + 1][i], w, a1);
      }
#pragma unroll 4
      for (int k = 0; k < NU; k += 4) {
        const float4 p0 = *(const float4*)&rh_lds[r0p3 + 0][k];
        const float4 p1 = *(const float4*)&rh_lds[r0p3 + 1][k];
        const float u0 = Up3[(k + 0) * NU];
        const float u1 = Up3[(k + 1) * NU];
        const float u2 = Up3[(k + 2) * NU];
        const float u3 = Up3[(k + 3) * NU];
        a0 = dot4(p0, u0, u1, u2, u3, a0);
        a1 = dot4(p1, u0, u1, u2, u3, a1);
      }
#pragma unroll
      for (int rr = 0; rr < 2; ++rr) {
        float pre = rr ? a1 : a0;
        float htw = fast_tanh(pre);
        int r = r0p3 + rr;
        float hold = h_lds[r][j];
        float zz = z_lds[r][j];
        float hnew = fmaf(zz, htw - hold, hold);
        h_lds[r][j] = hnew;
        states[(size_t)(t * BB + row0 + r) * NU + j] = hnew;
      }
    }
  }
  __syncthreads();
  for (int idx = tid; idx < 8 * NU; idx += 512)
    final_state[(size_t)row0 * NU + idx] = h_lds[idx >> 7][idx & 127];
}

// ---------------------------------------------------------------------------
// Pre-pack weights into bf16 MFMA B-fragment order.
// Fragment (n_tile,k_tile): lane l, elem e holds W[k_tile*32+(l>>4)*8+e][n_tile*16+(l&15)]
// Frag-blocks: Wb 16x4=64, Wpc 16x8=128, Whd(pad N=16) 1x8=8. Total 200.
// ---------------------------------------------------------------------------
__global__ __launch_bounds__(256) void prepack_kernel(
    const float* __restrict__ Wb, const float* __restrict__ Wpc,
    const float* __restrict__ Whd, short* __restrict__ Wb_pack,
    short* __restrict__ Wpc_pack, short* __restrict__ Whd_pack) {
  int t = blockIdx.x * 256 + threadIdx.x;
  if (t >= 200 * 64) return;
  int fb = t >> 6, lane = t & 63;
  const float* W;
  short* out;
  int n_tile, k_tile, N, local;
  if (fb < 64) {
    W = Wb; out = Wb_pack; local = fb; n_tile = fb >> 2; k_tile = fb & 3; N = 256;
  } else if (fb < 192) {
    int f = fb - 64;
    W = Wpc; out = Wpc_pack; local = f; n_tile = f >> 3; k_tile = f & 7; N = 256;
  } else {
    int f = fb - 192;
    W = Whd; out = Whd_pack; local = f; n_tile = 0; k_tile = f; N = 12;
  }
  short8 p;
#pragma unroll
  for (int e = 0; e < 8; ++e) {
    int k = k_tile * 32 + (lane >> 4) * 8 + e;
    int col = n_tile * 16 + (lane & 15);
    float v = (col < N) ? W[k * N + col] : 0.0f;
    p[e] = f2bf(v);
  }
  *((short8*)out + (local * 64 + lane)) = p;
}

// ---------------------------------------------------------------------------
// MFMA heads: 64 rows/block, 256 threads (4 waves, 16-row stripe each).
// states fp32 -> bf16 swizzled LDS; bneck -> fp32 out + bf16 swizzled LDS;
// pc/hd from LDS A-frags + prepacked global B-frags.
// LDS swizzle everywhere: byte_in_row ^= (row&7)<<4  (G4 fix for b128 reads)
// ---------------------------------------------------------------------------
__global__ __launch_bounds__(256, 3) void heads_mfma_kernel(
    const float* __restrict__ states, const short* __restrict__ Wb_pack,
    const short* __restrict__ Wpc_pack, const short* __restrict__ Whd_pack,
    const float* __restrict__ b_pc, const float* __restrict__ b_hd,
    float* __restrict__ out_hd, float* __restrict__ out_pc,
    float* __restrict__ out_bn) {
  __shared__ short s_lds[64 * 128];   // 16 KB  (row stride 256 B)
  __shared__ short bn_lds[64 * 256];  // 32 KB  (row stride 512 B)
  const int tid = threadIdx.x;
  const size_t R0 = (size_t)blockIdx.x * 64;

  // ---- stage states[64][128] fp32 -> bf16 LDS ----
  for (int c = tid; c < 1024; c += 256) {
    int row = c >> 4, s16 = c & 15;
    const float* src = states + (R0 + row) * 128 + s16 * 8;
    float4 v0 = *(const float4*)src;
    float4 v1 = *(const float4*)(src + 4);
    short8 p;
    p[0] = f2bf(v0.x); p[1] = f2bf(v0.y); p[2] = f2bf(v0.z); p[3] = f2bf(v0.w);
    p[4] = f2bf(v1.x); p[5] = f2bf(v1.y); p[6] = f2bf(v1.z); p[7] = f2bf(v1.w);
    int byte = row * 256 + ((s16 * 16) ^ ((row & 7) << 4));
    *(short8*)((char*)s_lds + byte) = p;
  }
  __syncthreads();

  const int lane = tid & 63;
  const int wave = tid >> 6;
  const int ln15 = lane & 15;  // A-row / D-col
  const int ln4 = lane >> 4;   // k-group / D-row-group
  const int r0 = wave * 16;    // wave's row stripe within block tile

  // ---- bneck: states[64,128]@Wb[128,256]; out fp32 + bf16 LDS ----
  {
    short8 a[4];
#pragma unroll
    for (int kt = 0; kt < 4; ++kt) {
      int byte =
          (r0 + ln15) * 256 + ((kt * 64 + ln4 * 16) ^ ((ln15 & 7) << 4));
      a[kt] = *(const short8*)((const char*)s_lds + byte);
    }
#pragma unroll
    for (int nt = 0; nt < 16; ++nt) {
      f32x4 acc = {0.f, 0.f, 0.f, 0.f};
      const short8* bp = (const short8*)Wb_pack + (nt * 4) * 64 + lane;
#pragma unroll
      for (int kt = 0; kt < 4; ++kt)
        acc = __builtin_amdgcn_mfma_f32_16x16x32_bf16(a[kt], bp[kt * 64], acc,
                                                      0, 0, 0);
      int col = nt * 16 + ln15;
#pragma unroll
      for (int q = 0; q < 4; ++q) {
        int row = r0 + ln4 * 4 + q;
        out_bn[(R0 + row) * NB + col] = acc[q];
        int byte = row * 512 + ((col * 2) ^ ((row & 7) << 4));
        *(short*)((char*)bn_lds + byte) = f2bf(acc[q]);
      }
    }
  }
  __syncthreads();

  // ---- pc + hd from bneck bf16 ----
  {
    short8 ab[8];
#pragma unroll
    for (int kt = 0; kt < 8; ++kt) {
      int byte =
          (r0 + ln15) * 512 + ((kt * 64 + ln4 * 16) ^ ((ln15 & 7) << 4));
      ab[kt] = *(const short8*)((const char*)bn_lds + byte);
    }
#pragma unroll
    for (int nt = 0; nt < 16; ++nt) {
      int col = nt * 16 + ln15;
      float bias = b_pc[col];
      f32x4 acc = {bias, bias, bias, bias};
      const short8* bp = (const short8*)Wpc_pack + (nt * 8) * 64 + lane;
#pragma unroll
      for (int kt = 0; kt < 8; ++kt)
        acc = __builtin_amdgcn_mfma_f32_16x16x32_bf16(ab[kt], bp[kt * 64], acc,
                                                      0, 0, 0);
#pragma unroll
      for (int q = 0; q < 4; ++q)
        out_pc[(R0 + r0 + ln4 * 4 + q) * NPC + col] = acc[q];
    }
    {
      int col = ln15;
      float bias = (col < NHD) ? b_hd[col] : 0.0f;
      f32x4 acc = {bias, bias, bias, bias};
      const short8* bp = (const short8*)Whd_pack + lane;
#pragma unroll
      for (int kt = 0; kt < 8; ++kt)
        acc = __builtin_amdgcn_mfma_f32_16x16x32_bf16(ab[kt], bp[kt * 64], acc,
                                                      0, 0, 0);
      if (col < NHD) {
#pragma unroll
        for (int q = 0; q < 4; ++q)
          out_hd[(R0 + r0 + ln4 * 4 + q) * NHD + col] = acc[q];
      }
    }
  }
}

// ---------------------------------------------------------------------------
extern "C" void kernel_launch(void* const* d_in, const int* in_sizes, int n_in,
                              void* d_out, int out_size, void* d_ws,
                              size_t ws_size, hipStream_t stream) {
  (void)in_sizes;
  (void)n_in;
  (void)out_size;
  (void)ws_size;
  const float* x = (const float*)d_in[0];
  const float* init_pc = (const float*)d_in[1];
  const float* init_hd = (const float*)d_in[2];
  const float* Wz = (const float*)d_in[3];
  const float* Wr = (const float*)d_in[4];
  const float* Wh = (const float*)d_in[5];
  const float* Uz = (const float*)d_in[6];
  const float* Ur = (const float*)d_in[7];
  const float* Uh = (const float*)d_in[8];
  const float* bz = (const float*)d_in[9];
  const float* br = (const float*)d_in[10];
  const float* bh = (const float*)d_in[11];
  const float* W_embed = (const float*)d_in[12];
  const float* b_embed = (const float*)d_in[13];
  const float* W_bneck = (const float*)d_in[14];
  const float* W_pc = (const float*)d_in[15];
  const float* b_pc = (const float*)d_in[16];
  const float* W_hd = (const float*)d_in[17];
  const float* b_hd = (const float*)d_in[18];

  float* out = (float*)d_out;
  float* out_hd = out;
  float* out_pc = out_hd + (size_t)TT * BB * NHD;
  float* out_bn = out_pc + (size_t)TT * BB * NPC;
  float* out_st = out_bn + (size_t)TT * BB * NB;
  float* out_fs = out_st + (size_t)TT * BB * NU;

  float* h0 = (float*)d_ws;  // 1 MB
  short* Wb_pack = (short*)((char*)d_ws + (1 << 20));  // 64 KB
  short* Wpc_pack = Wb_pack + 64 * 64 * 8;             // 128 KB
  short* Whd_pack = Wpc_pack + 128 * 64 * 8;           // 8 KB

  prepack_kernel<<<50, 256, 0, stream>>>(W_bneck, W_pc, W_hd, Wb_pack,
                                         Wpc_pack, Whd_pack);
  embed_kernel<<<BB / 2, 256, 0, stream>>>(init_pc, init_hd, W_embed, b_embed,
                                           h0);
  gru_kernel<<<BB / 8, 512, 0, stream>>>(x, h0, Wz, Wr, Wh, Uz, Ur, Uh, bz, br,
                                         bh, out_st, out_fs);
  heads_mfma_kernel<<<(TT * BB) / 64, 256, 0, stream>>>(
      out_st, Wb_pack, Wpc_pack, Whd_pack, b_pc, b_hd, out_hd, out_pc, out_bn);
}

// Round 3
// 380.457 us; speedup vs baseline: 3.7902x; 2.2649x over previous
//
#include <hip/hip_runtime.h>

#define TT 100
#define BB 2048
#define NI 3
#define NU 128
#define NB 256
#define NPC 256
#define NHD 12

typedef __attribute__((ext_vector_type(8))) short short8;
typedef __attribute__((ext_vector_type(4))) float f32x4;

__device__ __forceinline__ float fast_sigmoid(float x) {
  return 1.0f / (1.0f + __expf(-x));
}
__device__ __forceinline__ float fast_tanh(float x) {
  return 1.0f - 2.0f / (__expf(2.0f * x) + 1.0f);
}
__device__ __forceinline__ short f2bf(float f) {
  uint32_t u = __float_as_uint(f);
  u += 0x7FFF + ((u >> 16) & 1);  // RNE
  return (short)(u >> 16);
}
__device__ __forceinline__ float bf2f(short s) {
  return __uint_as_float(((uint32_t)(uint16_t)s) << 16);
}

// ---------------------------------------------------------------------------
// h0 = concat(init_pc, init_hd) @ W_embed + b_embed     [B, NU]
// ---------------------------------------------------------------------------
__global__ __launch_bounds__(256) void embed_kernel(
    const float* __restrict__ init_pc, const float* __restrict__ init_hd,
    const float* __restrict__ W_embed, const float* __restrict__ b_embed,
    float* __restrict__ h0) {
  __shared__ float pcs[2][NPC];
  __shared__ float hds[2][NHD];
  const int tid = threadIdx.x;
  const int b0 = blockIdx.x * 2;

  for (int idx = tid; idx < 2 * NPC; idx += 256)
    pcs[idx >> 8][idx & 255] =
        init_pc[(size_t)(b0 + (idx >> 8)) * NPC + (idx & 255)];
  if (tid < 2 * NHD) {
    int rr = tid / NHD, cc = tid - rr * NHD;
    hds[rr][cc] = init_hd[(size_t)(b0 + rr) * NHD + cc];
  }
  __syncthreads();

  const int half = tid >> 7;
  const int j = tid & 127;
  const float* Wp = W_embed + j;
  float a0 = 0.f, a1 = 0.f, a2 = 0.f, a3 = 0.f;
#pragma unroll 4
  for (int k = 0; k < NPC; k += 4) {
    a0 = fmaf(pcs[half][k + 0], Wp[(k + 0) * NU], a0);
    a1 = fmaf(pcs[half][k + 1], Wp[(k + 1) * NU], a1);
    a2 = fmaf(pcs[half][k + 2], Wp[(k + 2) * NU], a2);
    a3 = fmaf(pcs[half][k + 3], Wp[(k + 3) * NU], a3);
  }
#pragma unroll
  for (int k = 0; k < NHD; ++k)
    a0 = fmaf(hds[half][k], Wp[(NPC + k) * NU], a0);
  float acc = b_embed[j] + ((a0 + a1) + (a2 + a3));
  h0[(size_t)(b0 + half) * NU + j] = acc;
}

// ---------------------------------------------------------------------------
// MFMA GRU scan. 256 blocks x 8 batch rows (M padded to 16), 512 thr = 8 waves.
// Wave w owns gate/h-tilde columns 16w..16w+15; Uz/Ur/Uh columns live in VGPRs
// as pre-split (hi/lo bf16) B-fragments. h master copy in D-layout registers.
// rh and h cross waves via XOR-swizzled bf16 hi/lo LDS planes ([16][128],
// pad rows 8-15 zeroed once). Split-precision: hi*hi + lo*hi + hi*lo per tile.
// ---------------------------------------------------------------------------
__global__ __launch_bounds__(512, 2) void gru_mfma_kernel(
    const float* __restrict__ x, const float* __restrict__ h0,
    const float* __restrict__ Wz, const float* __restrict__ Wr,
    const float* __restrict__ Wh, const float* __restrict__ Uz,
    const float* __restrict__ Ur, const float* __restrict__ Uh,
    const float* __restrict__ bz, const float* __restrict__ br,
    const float* __restrict__ bh, float* __restrict__ states,
    float* __restrict__ final_state) {
  __shared__ short h_hi[16 * 128];
  __shared__ short h_lo[16 * 128];
  __shared__ short p_hi[16 * 128];
  __shared__ short p_lo[16 * 128];
  __shared__ float xt_lds[2][8][4];

  const int tid = threadIdx.x;
  const int lane = tid & 63;
  const int w = tid >> 6;
  const int ln15 = lane & 15;
  const int g4 = lane >> 4;
  const int col = w * 16 + ln15;  // this lane's gate/feature column
  const int row0 = blockIdx.x * 8;

  // per-lane input-projection weights (column slice)
  const float wz0 = Wz[col], wz1 = Wz[NU + col], wz2 = Wz[2 * NU + col];
  const float wr0 = Wr[col], wr1 = Wr[NU + col], wr2 = Wr[2 * NU + col];
  const float wh0 = Wh[col], wh1 = Wh[NU + col], wh2 = Wh[2 * NU + col];
  const float bzv = bz[col], brv = br[col], bhv = bh[col];

  // U B-fragments, hi/lo split: lane holds U[kt*32+g4*8+e][col]
  short8 Uzh[4], Uzl[4], Urh[4], Url[4], Uhh[4], Uhl[4];
#pragma unroll
  for (int kt = 0; kt < 4; ++kt) {
#pragma unroll
    for (int e = 0; e < 8; ++e) {
      const int kk = kt * 32 + g4 * 8 + e;
      float v;
      short hi;
      v = Uz[kk * NU + col];
      hi = f2bf(v);
      Uzh[kt][e] = hi;
      Uzl[kt][e] = f2bf(v - bf2f(hi));
      v = Ur[kk * NU + col];
      hi = f2bf(v);
      Urh[kt][e] = hi;
      Url[kt][e] = f2bf(v - bf2f(hi));
      v = Uh[kk * NU + col];
      hi = f2bf(v);
      Uhh[kt][e] = hi;
      Uhl[kt][e] = f2bf(v - bf2f(hi));
    }
  }

  // init h in D-layout registers + build swizzled planes (pad rows -> 0)
  float hreg[4];
#pragma unroll
  for (int q = 0; q < 4; ++q) {
    const int row = g4 * 4 + q;
    hreg[q] = (row < 8) ? h0[(size_t)(row0 + row) * NU + col] : 0.0f;
    const int off = row * 256 + ((col * 2) ^ ((row & 7) << 4));
    const short hi = f2bf(hreg[q]);
    *(short*)((char*)h_hi + off) = hi;
    *(short*)((char*)h_lo + off) = f2bf(hreg[q] - bf2f(hi));
  }
  if (tid < 24) {
    const int r = tid / 3, i = tid - r * 3;
    xt_lds[0][r][i] = x[(size_t)(row0 + r) * NI + i];
  }
  __syncthreads();

  for (int t = 0; t < TT; ++t) {
    const int pb = t & 1;

    // ---- read h A-fragments ----
    short8 ahi[4], alo[4];
#pragma unroll
    for (int kt = 0; kt < 4; ++kt) {
      const int off = ln15 * 256 + ((kt * 64 + g4 * 16) ^ ((ln15 & 7) << 4));
      ahi[kt] = *(const short8*)((const char*)h_hi + off);
      alo[kt] = *(const short8*)((const char*)h_lo + off);
    }

    // ---- x rows + gate acc init (bias + x@W) ----
    float4 xrow[4];
#pragma unroll
    for (int q = 0; q < 4; ++q)
      xrow[q] = *(const float4*)xt_lds[pb][(g4 * 4 + q) & 7];
    f32x4 zacc, racc;
#pragma unroll
    for (int q = 0; q < 4; ++q) {
      zacc[q] =
          fmaf(xrow[q].x, wz0, fmaf(xrow[q].y, wz1, fmaf(xrow[q].z, wz2, bzv)));
      racc[q] =
          fmaf(xrow[q].x, wr0, fmaf(xrow[q].y, wr1, fmaf(xrow[q].z, wr2, brv)));
    }

    // ---- gates MFMA (split precision) ----
#pragma unroll
    for (int kt = 0; kt < 4; ++kt) {
      zacc = __builtin_amdgcn_mfma_f32_16x16x32_bf16(ahi[kt], Uzh[kt], zacc, 0, 0, 0);
      racc = __builtin_amdgcn_mfma_f32_16x16x32_bf16(ahi[kt], Urh[kt], racc, 0, 0, 0);
      zacc = __builtin_amdgcn_mfma_f32_16x16x32_bf16(alo[kt], Uzh[kt], zacc, 0, 0, 0);
      racc = __builtin_amdgcn_mfma_f32_16x16x32_bf16(alo[kt], Urh[kt], racc, 0, 0, 0);
      zacc = __builtin_amdgcn_mfma_f32_16x16x32_bf16(ahi[kt], Uzl[kt], zacc, 0, 0, 0);
      racc = __builtin_amdgcn_mfma_f32_16x16x32_bf16(ahi[kt], Url[kt], racc, 0, 0, 0);
    }

    // ---- z, r, rh; write rh planes (real rows only) ----
    float zg[4], rh[4];
#pragma unroll
    for (int q = 0; q < 4; ++q) {
      zg[q] = fast_sigmoid(zacc[q]);
      rh[q] = fast_sigmoid(racc[q]) * hreg[q];
    }
    if (g4 < 2) {
#pragma unroll
      for (int q = 0; q < 4; ++q) {
        const int row = g4 * 4 + q;
        const int off = row * 256 + ((col * 2) ^ ((row & 7) << 4));
        const short hi = f2bf(rh[q]);
        *(short*)((char*)p_hi + off) = hi;
        *(short*)((char*)p_lo + off) = f2bf(rh[q] - bf2f(hi));
      }
    }
    __syncthreads();  // rh planes visible

    // ---- stage next x (into the other buffer) ----
    if (t + 1 < TT && tid < 24) {
      const int r = tid / 3, i = tid - r * 3;
      xt_lds[pb ^ 1][r][i] = x[(size_t)((t + 1) * BB + row0 + r) * NI + i];
    }

    // ---- h-tilde MFMA ----
    short8 phi[4], plo[4];
#pragma unroll
    for (int kt = 0; kt < 4; ++kt) {
      const int off = ln15 * 256 + ((kt * 64 + g4 * 16) ^ ((ln15 & 7) << 4));
      phi[kt] = *(const short8*)((const char*)p_hi + off);
      plo[kt] = *(const short8*)((const char*)p_lo + off);
    }
    f32x4 hacc;
#pragma unroll
    for (int q = 0; q < 4; ++q)
      hacc[q] =
          fmaf(xrow[q].x, wh0, fmaf(xrow[q].y, wh1, fmaf(xrow[q].z, wh2, bhv)));
#pragma unroll
    for (int kt = 0; kt < 4; ++kt) {
      hacc = __builtin_amdgcn_mfma_f32_16x16x32_bf16(phi[kt], Uhh[kt], hacc, 0, 0, 0);
      hacc = __builtin_amdgcn_mfma_f32_16x16x32_bf16(plo[kt], Uhh[kt], hacc, 0, 0, 0);
      hacc = __builtin_amdgcn_mfma_f32_16x16x32_bf16(phi[kt], Uhl[kt], hacc, 0, 0, 0);
    }

    // ---- update h, store states, write h planes ----
#pragma unroll
    for (int q = 0; q < 4; ++q) {
      const float htw = fast_tanh(hacc[q]);
      hreg[q] = fmaf(zg[q], htw - hreg[q], hreg[q]);
    }
    if (g4 < 2) {
#pragma unroll
      for (int q = 0; q < 4; ++q) {
        const int row = g4 * 4 + q;
        states[((size_t)t * BB + row0 + row) * NU + col] = hreg[q];
        const int off = row * 256 + ((col * 2) ^ ((row & 7) << 4));
        const short hi = f2bf(hreg[q]);
        *(short*)((char*)h_hi + off) = hi;
        *(short*)((char*)h_lo + off) = f2bf(hreg[q] - bf2f(hi));
      }
    }
    __syncthreads();  // h planes + next xt visible
  }

  if (g4 < 2) {
#pragma unroll
    for (int q = 0; q < 4; ++q) {
      const int row = g4 * 4 + q;
      final_state[(size_t)(row0 + row) * NU + col] = hreg[q];
    }
  }
}

// ---------------------------------------------------------------------------
// Pre-pack weights into bf16 MFMA B-fragment order.
// ---------------------------------------------------------------------------
__global__ __launch_bounds__(256) void prepack_kernel(
    const float* __restrict__ Wb, const float* __restrict__ Wpc,
    const float* __restrict__ Whd, short* __restrict__ Wb_pack,
    short* __restrict__ Wpc_pack, short* __restrict__ Whd_pack) {
  int t = blockIdx.x * 256 + threadIdx.x;
  if (t >= 200 * 64) return;
  int fb = t >> 6, lane = t & 63;
  const float* W;
  short* out;
  int n_tile, k_tile, N, local;
  if (fb < 64) {
    W = Wb; out = Wb_pack; local = fb; n_tile = fb >> 2; k_tile = fb & 3; N = 256;
  } else if (fb < 192) {
    int f = fb - 64;
    W = Wpc; out = Wpc_pack; local = f; n_tile = f >> 3; k_tile = f & 7; N = 256;
  } else {
    int f = fb - 192;
    W = Whd; out = Whd_pack; local = f; n_tile = 0; k_tile = f; N = 12;
  }
  short8 p;
#pragma unroll
  for (int e = 0; e < 8; ++e) {
    int k = k_tile * 32 + (lane >> 4) * 8 + e;
    int colc = n_tile * 16 + (lane & 15);
    float v = (colc < N) ? W[k * N + colc] : 0.0f;
    p[e] = f2bf(v);
  }
  *((short8*)out + (local * 64 + lane)) = p;
}

// ---------------------------------------------------------------------------
// MFMA heads: 64 rows/block, 256 threads (4 waves, 16-row stripe each).
// ---------------------------------------------------------------------------
__global__ __launch_bounds__(256, 3) void heads_mfma_kernel(
    const float* __restrict__ states, const short* __restrict__ Wb_pack,
    const short* __restrict__ Wpc_pack, const short* __restrict__ Whd_pack,
    const float* __restrict__ b_pc, const float* __restrict__ b_hd,
    float* __restrict__ out_hd, float* __restrict__ out_pc,
    float* __restrict__ out_bn) {
  __shared__ short s_lds[64 * 128];   // 16 KB
  __shared__ short bn_lds[64 * 256];  // 32 KB
  const int tid = threadIdx.x;
  const size_t R0 = (size_t)blockIdx.x * 64;

  for (int c = tid; c < 1024; c += 256) {
    int row = c >> 4, s16 = c & 15;
    const float* src = states + (R0 + row) * 128 + s16 * 8;
    float4 v0 = *(const float4*)src;
    float4 v1 = *(const float4*)(src + 4);
    short8 p;
    p[0] = f2bf(v0.x); p[1] = f2bf(v0.y); p[2] = f2bf(v0.z); p[3] = f2bf(v0.w);
    p[4] = f2bf(v1.x); p[5] = f2bf(v1.y); p[6] = f2bf(v1.z); p[7] = f2bf(v1.w);
    int byte = row * 256 + ((s16 * 16) ^ ((row & 7) << 4));
    *(short8*)((char*)s_lds + byte) = p;
  }
  __syncthreads();

  const int lane = tid & 63;
  const int wave = tid >> 6;
  const int ln15 = lane & 15;
  const int ln4 = lane >> 4;
  const int r0 = wave * 16;

  {
    short8 a[4];
#pragma unroll
    for (int kt = 0; kt < 4; ++kt) {
      int byte =
          (r0 + ln15) * 256 + ((kt * 64 + ln4 * 16) ^ ((ln15 & 7) << 4));
      a[kt] = *(const short8*)((const char*)s_lds + byte);
    }
#pragma unroll
    for (int nt = 0; nt < 16; ++nt) {
      f32x4 acc = {0.f, 0.f, 0.f, 0.f};
      const short8* bp = (const short8*)Wb_pack + (nt * 4) * 64 + lane;
#pragma unroll
      for (int kt = 0; kt < 4; ++kt)
        acc = __builtin_amdgcn_mfma_f32_16x16x32_bf16(a[kt], bp[kt * 64], acc,
                                                      0, 0, 0);
      int colc = nt * 16 + ln15;
#pragma unroll
      for (int q = 0; q < 4; ++q) {
        int row = r0 + ln4 * 4 + q;
        out_bn[(R0 + row) * NB + colc] = acc[q];
        int byte = row * 512 + ((colc * 2) ^ ((row & 7) << 4));
        *(short*)((char*)bn_lds + byte) = f2bf(acc[q]);
      }
    }
  }
  __syncthreads();

  {
    short8 ab[8];
#pragma unroll
    for (int kt = 0; kt < 8; ++kt) {
      int byte =
          (r0 + ln15) * 512 + ((kt * 64 + ln4 * 16) ^ ((ln15 & 7) << 4));
      ab[kt] = *(const short8*)((const char*)bn_lds + byte);
    }
#pragma unroll
    for (int nt = 0; nt < 16; ++nt) {
      int colc = nt * 16 + ln15;
      float bias = b_pc[colc];
      f32x4 acc = {bias, bias, bias, bias};
      const short8* bp = (const short8*)Wpc_pack + (nt * 8) * 64 + lane;
#pragma unroll
      for (int kt = 0; kt < 8; ++kt)
        acc = __builtin_amdgcn_mfma_f32_16x16x32_bf16(ab[kt], bp[kt * 64], acc,
                                                      0, 0, 0);
#pragma unroll
      for (int q = 0; q < 4; ++q)
        out_pc[(R0 + r0 + ln4 * 4 + q) * NPC + colc] = acc[q];
    }
    {
      int colc = ln15;
      float bias = (colc < NHD) ? b_hd[colc] : 0.0f;
      f32x4 acc = {bias, bias, bias, bias};
      const short8* bp = (const short8*)Whd_pack + lane;
#pragma unroll
      for (int kt = 0; kt < 8; ++kt)
        acc = __builtin_amdgcn_mfma_f32_16x16x32_bf16(ab[kt], bp[kt * 64], acc,
                                                      0, 0, 0);
      if (colc < NHD) {
#pragma unroll
        for (int q = 0; q < 4; ++q)
          out_hd[(R0 + r0 + ln4 * 4 + q) * NHD + colc] = acc[q];
      }
    }
  }
}

// ---------------------------------------------------------------------------
extern "C" void kernel_launch(void* const* d_in, const int* in_sizes, int n_in,
                              void* d_out, int out_size, void* d_ws,
                              size_t ws_size, hipStream_t stream) {
  (void)in_sizes;
  (void)n_in;
  (void)out_size;
  (void)ws_size;
  const float* x = (const float*)d_in[0];
  const float* init_pc = (const float*)d_in[1];
  const float* init_hd = (const float*)d_in[2];
  const float* Wz = (const float*)d_in[3];
  const float* Wr = (const float*)d_in[4];
  const float* Wh = (const float*)d_in[5];
  const float* Uz = (const float*)d_in[6];
  const float* Ur = (const float*)d_in[7];
  const float* Uh = (const float*)d_in[8];
  const float* bz = (const float*)d_in[9];
  const float* br = (const float*)d_in[10];
  const float* bh = (const float*)d_in[11];
  const float* W_embed = (const float*)d_in[12];
  const float* b_embed = (const float*)d_in[13];
  const float* W_bneck = (const float*)d_in[14];
  const float* W_pc = (const float*)d_in[15];
  const float* b_pc = (const float*)d_in[16];
  const float* W_hd = (const float*)d_in[17];
  const float* b_hd = (const float*)d_in[18];

  float* out = (float*)d_out;
  float* out_hd = out;
  float* out_pc = out_hd + (size_t)TT * BB * NHD;
  float* out_bn = out_pc + (size_t)TT * BB * NPC;
  float* out_st = out_bn + (size_t)TT * BB * NB;
  float* out_fs = out_st + (size_t)TT * BB * NU;

  float* h0 = (float*)d_ws;                            // 1 MB
  short* Wb_pack = (short*)((char*)d_ws + (1 << 20));  // 64 KB
  short* Wpc_pack = Wb_pack + 64 * 64 * 8;             // 128 KB
  short* Whd_pack = Wpc_pack + 128 * 64 * 8;           // 8 KB

  prepack_kernel<<<50, 256, 0, stream>>>(W_bneck, W_pc, W_hd, Wb_pack,
                                         Wpc_pack, Whd_pack);
  embed_kernel<<<BB / 2, 256, 0, stream>>>(init_pc, init_hd, W_embed, b_embed,
                                           h0);
  gru_mfma_kernel<<<BB / 8, 512, 0, stream>>>(x, h0, Wz, Wr, Wh, Uz, Ur, Uh,
                                              bz, br, bh, out_st, out_fs);
  heads_mfma_kernel<<<(TT * BB) / 64, 256, 0, stream>>>(
      out_st, Wb_pack, Wpc_pack, Whd_pack, b_pc, b_hd, out_hd, out_pc, out_bn);
}